// Round 16
// baseline (169.951 us; speedup 1.0000x reference)
//
#include <hip/hip_runtime.h>
#include <hip/hip_bf16.h>
#include <math.h>

#define TT   2048
#define KK   48
#define KP   68             // epilogue staging pitch in ushorts

typedef __attribute__((ext_vector_type(8))) short bf16x8;
typedef __attribute__((ext_vector_type(4))) float f32x4;
typedef __attribute__((ext_vector_type(4))) unsigned int u32x4;
typedef unsigned short ushort_t;

union FragU { u32x4 u; bf16x8 h; };

__device__ __forceinline__ float rlf(float x, int l) {
    return __uint_as_float((unsigned)__builtin_amdgcn_readlane((int)__float_as_uint(x), l));
}
__device__ __forceinline__ unsigned pk2(float a, float b) {
    __hip_bfloat162 h = __float22bfloat162_rn(make_float2(a, b));
    return *(unsigned*)&h;
}
// HW pack: single v_cvt_pk_bf16_f32 (RNE; gfx950-verified R7: -45us)
__device__ __forceinline__ unsigned pk2a(float a, float b) {
    unsigned r;
    asm("v_cvt_pk_bf16_f32 %0, %1, %2" : "=v"(r) : "v"(a), "v"(b));
    return r;
}

// ---------------- Kernel 1: segment matrix products (R16: y ping-pong) ------
// R15 PMC: MFMA 46% + VALU 49%, sum ~95%, zero overlap. Cause: one shared
// y0..y2 set -> WAR chain MFMA(0)->SCALE(0)->MFMA(1)->SCALE(1)->... strictly
// alternating pipe bursts. Fix: yA/yB ping-pong + pipelined order
// MFMA(0,yA); MFMA(1,yB); SCALE(0,yA); MFMA(2,yA); SCALE(1,yB); SCALE(2,yA)
// -> MFMA and VALU of independent columns can co-issue; next step's MFMA(0)
// (deps: Bf[0] only) overlaps this step's SCALE(1,2).
template <int SEGT, int NSEGT>
__global__ __launch_bounds__(64, 4) void crf_seg_kernel(
    const float* __restrict__ logits,   // [B, T, K]
    const float* __restrict__ trans,    // [K, K]
    const int*   __restrict__ lens,     // [B]
    ushort_t*    __restrict__ Qout,     // [B*NSEGT][48*48] bf16 row-major
    float*       __restrict__ sigout)   // [B*NSEGT]
{
    constexpr int NFULLT = NSEGT - 1;
    const int b    = blockIdx.x;
    const int seg  = blockIdx.y;        // 0..NSEGT-1
    const int job  = b * NSEGT + seg;
    const int lane = threadIdx.x;
    const int c = lane & 15, g = lane >> 4;

    int t0, t1;
    if (seg < NFULLT) { t0 = SEGT * seg + 1; t1 = SEGT * seg + SEGT; }
    else {
        int L  = lens[b];
        int nf = (L >= 2) ? (L - 1) / SEGT : 0;
        if (nf > NFULLT) nf = NFULLT;
        t0 = SEGT * nf + 1; t1 = L - 1;   // may be empty (t1 < t0) -> Q = I
    }

    __shared__ float    eLs[2][64];
    __shared__ ushort_t Qst[KK * KP];    // epilogue staging only

    // Constant A fragments: A[mt][q], row r = 16mt + c, k per bijection
    // k = 32q + 16*(e>>2) + 4g + (e&3); zero for k >= 48.
    FragU A[3][2];
    #pragma unroll
    for (int mt = 0; mt < 3; ++mt) {
        const int r = 16 * mt + c;
        #pragma unroll
        for (int q = 0; q < 2; ++q) {
            #pragma unroll
            for (int ep = 0; ep < 4; ++ep) {
                float v0, v1;
                { int e = 2 * ep;     int kk = 32 * q + 16 * (e >> 2) + 4 * g + (e & 3);
                  v0 = (kk < KK) ? __expf(trans[kk * KK + r]) : 0.f; }
                { int e = 2 * ep + 1; int kk = 32 * q + 16 * (e >> 2) + 4 * g + (e & 3);
                  v1 = (kk < KK) ? __expf(trans[kk * KK + r]) : 0.f; }
                A[mt][q].u[ep] = pk2(v0, v1);
            }
        }
    }

    // Bf init = identity columns: elem (q,e) of tile nt = I[k][16nt+c].
    FragU Bf[3][2];
    #pragma unroll
    for (int nt = 0; nt < 3; ++nt) {
        const int n = 16 * nt + c;
        #pragma unroll
        for (int q = 0; q < 2; ++q) {
            #pragma unroll
            for (int ep = 0; ep < 4; ++ep) {
                int e0 = 2 * ep, e1 = 2 * ep + 1;
                int k0 = 32 * q + 16 * (e0 >> 2) + 4 * g + (e0 & 3);
                int k1 = 32 * q + 16 * (e1 >> 2) + 4 * g + (e1 & 3);
                unsigned lo = (k0 == n) ? 0x3F80u : 0u;
                unsigned hi = (k1 == n) ? 0x3F80u : 0u;
                Bf[nt][q].u[ep] = (hi << 16) | lo;
            }
        }
    }

    const float* lg_b = logits + (size_t)b * TT * KK;
    const int jj = (lane < KK) ? lane : 0;
    float sg = 0.f;
    const int nsteps = t1 - t0 + 1;

    f32x4 z4 = {0.f, 0.f, 0.f, 0.f};
    asm("" : "+v"(z4));

// Scale col nt_'s Y regs by es, cvt to bf16, store into Bf[nt_] (guarded).
#define SCALE_STORE(nt_, Y0_, Y1_, Y2_)                                       \
    {                                                                         \
        f32x4 w0 = Y0_ * es0, w1 = Y1_ * es1, w2 = Y2_ * es2;                 \
        unsigned n0 = pk2a(w0[0], w0[1]);                                     \
        unsigned n1 = pk2a(w0[2], w0[3]);                                     \
        unsigned n2 = pk2a(w1[0], w1[1]);                                     \
        unsigned n3 = pk2a(w1[2], w1[3]);                                     \
        unsigned n4 = pk2a(w2[0], w2[1]);                                     \
        unsigned n5 = pk2a(w2[2], w2[3]);                                     \
        if (G_) {                                                             \
            Bf[nt_][0].u[0] = jk ? Bf[nt_][0].u[0] : n0;                      \
            Bf[nt_][0].u[1] = jk ? Bf[nt_][0].u[1] : n1;                      \
            Bf[nt_][0].u[2] = jk ? Bf[nt_][0].u[2] : n2;                      \
            Bf[nt_][0].u[3] = jk ? Bf[nt_][0].u[3] : n3;                      \
            Bf[nt_][1].u[0] = jk ? Bf[nt_][1].u[0] : n4;                      \
            Bf[nt_][1].u[1] = jk ? Bf[nt_][1].u[1] : n5;                      \
        } else {                                                              \
            Bf[nt_][0].u[0] = n0; Bf[nt_][0].u[1] = n1;                       \
            Bf[nt_][0].u[2] = n2; Bf[nt_][0].u[3] = n3;                       \
            Bf[nt_][1].u[0] = n4; Bf[nt_][1].u[1] = n5;                       \
        }                                                                     \
    }

#define COL_MFMA(nt_, Y0_, Y1_, Y2_)                                          \
        __builtin_amdgcn_s_setprio(1);                                        \
        Y0_ = __builtin_amdgcn_mfma_f32_16x16x32_bf16(A[0][0].h, Bf[nt_][0].h, z4, 0, 0, 0); \
        Y0_ = __builtin_amdgcn_mfma_f32_16x16x32_bf16(A[0][1].h, Bf[nt_][1].h, Y0_, 0, 0, 0); \
        Y1_ = __builtin_amdgcn_mfma_f32_16x16x32_bf16(A[1][0].h, Bf[nt_][0].h, z4, 0, 0, 0); \
        Y1_ = __builtin_amdgcn_mfma_f32_16x16x32_bf16(A[1][1].h, Bf[nt_][1].h, Y1_, 0, 0, 0); \
        Y2_ = __builtin_amdgcn_mfma_f32_16x16x32_bf16(A[2][0].h, Bf[nt_][0].h, z4, 0, 0, 0); \
        Y2_ = __builtin_amdgcn_mfma_f32_16x16x32_bf16(A[2][1].h, Bf[nt_][1].h, Y2_, 0, 0, 0); \
        __builtin_amdgcn_s_setprio(0);

// RN_: renormalize this step (every 4th: u_ = 3, 7).
#define STEP(u_, GG_, RN_)                                                    \
    {                                                                         \
        constexpr bool G_ = (GG_);                                            \
        const int i = 8 * cs + (u_);                                          \
        f32x4 eL0 = *(const f32x4*)&eLs[par][4 * g];                          \
        f32x4 eL1 = *(const f32x4*)&eLs[par][16 + 4 * g];                     \
        f32x4 eL2 = *(const f32x4*)&eLs[par][32 + 4 * g];                     \
        float lgn = pf[((u_) + 1) & 7];                                       \
        int nr = t0 + i + 9; if (nr > TT - 1) nr = TT - 1;                    \
        pf[((u_) + 1) & 7] = lg_b[nr * KK + jj];                              \
        if (lane < KK) eLs[par ^ 1][lane] = __expf(lgn);                      \
        const bool jk = G_ ? (i >= nsteps) : false;                           \
        f32x4 yA0, yA1, yA2, yB0, yB1, yB2;                                   \
        COL_MFMA(0, yA0, yA1, yA2)                                            \
        COL_MFMA(1, yB0, yB1, yB2)                                            \
        f32x4 es0, es1, es2;                                                  \
        if (RN_) {                                                            \
            float r = __uint_as_float((unsigned)                              \
                __builtin_amdgcn_readfirstlane((int)__float_as_uint(yA0[0])));\
            float rr = __builtin_amdgcn_rcpf(r);                              \
            sg += jk ? 0.f : __logf(r);                                       \
            es0 = eL0 * rr; es1 = eL1 * rr; es2 = eL2 * rr;                   \
        } else {                                                              \
            es0 = eL0; es1 = eL1; es2 = eL2;                                  \
        }                                                                     \
        SCALE_STORE(0, yA0, yA1, yA2)                                         \
        COL_MFMA(2, yA0, yA1, yA2)                                            \
        SCALE_STORE(1, yB0, yB1, yB2)                                         \
        SCALE_STORE(2, yA0, yA1, yA2)                                         \
        par ^= 1;                                                             \
    }

    int par = 0;
    if (nsteps > 0) {
        if (lane < KK) eLs[0][lane] = __expf(lg_b[t0 * KK + jj]);
        float pf[8];
        #pragma unroll
        for (int j = 1; j < 8; ++j) {
            int rj = t0 + j; if (rj > TT - 1) rj = TT - 1;
            pf[j] = lg_b[rj * KK + jj];
        }
        { int rj = t0 + 8; if (rj > TT - 1) rj = TT - 1; pf[0] = lg_b[rj * KK + jj]; }

        const int nchunks = (nsteps + 7) / 8;
        #pragma unroll 1
        for (int cs = 0; cs < nchunks - 1; ++cs) {
            STEP(0, false, false) STEP(1, false, false)
            STEP(2, false, false) STEP(3, false, true)
            STEP(4, false, false) STEP(5, false, false)
            STEP(6, false, false) STEP(7, false, true)
        }
        {   // last chunk: junk-guarded (freezes Bf/sg for i >= nsteps)
            const int cs = nchunks - 1;
            STEP(0, true, false) STEP(1, true, false)
            STEP(2, true, false) STEP(3, true, true)
            STEP(4, true, false) STEP(5, true, false)
            STEP(6, true, false) STEP(7, true, true)
        }
    }
#undef STEP
#undef COL_MFMA
#undef SCALE_STORE

    // ---- epilogue: stage Bf (= final Q, bf16, maybe unnormalized) to LDS ----
    #pragma unroll
    for (int nt = 0; nt < 3; ++nt) {
        ushort_t* basep = &Qst[(16 * nt + c) * KP];
        *(unsigned*)&basep[4 * g]          = Bf[nt][0].u[0];
        *(unsigned*)&basep[4 * g + 2]      = Bf[nt][0].u[1];
        *(unsigned*)&basep[16 + 4 * g]     = Bf[nt][0].u[2];
        *(unsigned*)&basep[16 + 4 * g + 2] = Bf[nt][0].u[3];
        *(unsigned*)&basep[32 + 4 * g]     = Bf[nt][1].u[0];
        *(unsigned*)&basep[32 + 4 * g + 2] = Bf[nt][1].u[1];
    }
    __syncthreads();

    if (lane < KK) {
        const int m = lane;
        unsigned w[24];
        #pragma unroll
        for (int np = 0; np < 24; ++np) {
            unsigned lo = Qst[(2 * np)     * KP + m];
            unsigned hi = Qst[(2 * np + 1) * KP + m];
            w[np] = (hi << 16) | lo;
        }
        ushort_t* dst = Qout + (size_t)job * (KK * KK) + m * KK;
        #pragma unroll
        for (int i4 = 0; i4 < 6; ++i4) {
            uint4 o; o.x = w[4*i4]; o.y = w[4*i4+1]; o.z = w[4*i4+2]; o.w = w[4*i4+3];
            *(uint4*)&dst[8 * i4] = o;
        }
    }
    if (lane == 0) sigout[job] = sg;
}

// ---------------- Kernel 2: per-batch combine + scores (proven R5-R15) ----
template <int SEGT, int NSEGT>
__global__ __launch_bounds__(64) void crf_comb_kernel(
    const float* __restrict__ logits, const float* __restrict__ trans,
    const int* __restrict__ targets, const int* __restrict__ lens,
    const ushort_t* __restrict__ Qall, const float* __restrict__ sig,
    float* __restrict__ out)
{
    constexpr int NFULLT = NSEGT - 1;
    const int b = blockIdx.x, lane = threadIdx.x;
    const int jj = (lane < KK) ? lane : 0;
    const int L = lens[b];

    __shared__ float s_trans[KK * KK];
    for (int k = lane; k < KK * KK; k += 64) s_trans[k] = trans[k];
    __syncthreads();

    const float* lg_b = logits  + (size_t)b * TT * KK;
    const int*   tg_b = targets + (size_t)b * TT;

    float ub = 0.f;
    #pragma unroll 4
    for (int t = lane; t < TT; t += 64) {
        if (t < L) {
            int tg = tg_b[t];
            ub += lg_b[t * KK + tg];
            if (t >= 1) { int tp = tg_b[t - 1]; ub += s_trans[tp * KK + tg]; }
        }
    }
    #pragma unroll
    for (int d = 32; d >= 1; d >>= 1) ub += __shfl_xor(ub, d, 64);

    float log_norm = 0.f;
    if (L > 0) {
        float a0 = lg_b[jj];
        float M  = rlf(a0, 0);
        float s  = (lane < KK) ? __expf(a0 - M) : 0.f;
        int nf = (L >= 2) ? (L - 1) / SEGT : 0;
        if (nf > NFULLT) nf = NFULLT;

        for (int ci = 0; ci <= nf; ++ci) {           // full segments, then tail
            const int job = b * NSEGT + ((ci < nf) ? ci : NFULLT);
            const ushort_t* Qr = Qall + (size_t)job * (KK * KK) + jj * KK;
            unsigned rw[24];
            #pragma unroll
            for (int i4 = 0; i4 < 6; ++i4) {
                uint4 v = *(const uint4*)&Qr[8 * i4];
                rw[4*i4] = v.x; rw[4*i4+1] = v.y; rw[4*i4+2] = v.z; rw[4*i4+3] = v.w;
            }
            float acc = 0.f;
            #pragma unroll
            for (int ip = 0; ip < 24; ++ip) {
                unsigned u = rw[ip];
                float q0 = __uint_as_float(u << 16);
                float q1 = __uint_as_float(u & 0xFFFF0000u);
                acc = fmaf(rlf(s, 2 * ip),     q0, acc);
                acc = fmaf(rlf(s, 2 * ip + 1), q1, acc);
            }
            float r  = rlf(acc, 0);
            float rr = __builtin_amdgcn_rcpf(r);
            s = (lane < KK) ? acc * rr : 0.f;
            M += __logf(r) + sig[job];
        }

        float ssum = (lane < KK) ? s : 0.f;
        #pragma unroll
        for (int d = 32; d >= 1; d >>= 1) ssum += __shfl_xor(ssum, d, 64);
        log_norm = M + __logf(ssum);
    }

    if (lane == 0) out[b] = (L <= 0) ? 0.f : (ub - log_norm);
}

// ---------------- Round-3 fallback (ws too small) ----------------
__global__ __launch_bounds__(64) void crf_fwd_fallback(
    const float* __restrict__ logits, const float* __restrict__ trans,
    const int* __restrict__ targets, const int* __restrict__ lens,
    float* __restrict__ out)
{
    const int b = blockIdx.x, lane = threadIdx.x;
    const int jj = (lane < KK) ? lane : 0;
    const int L = lens[b];
    __shared__ float s_trans[KK * KK];
    for (int k = lane; k < KK * KK; k += 64) s_trans[k] = trans[k];
    float et[KK];
    #pragma unroll
    for (int i = 0; i < KK; ++i) et[i] = __expf(trans[i * KK + jj]);
    __syncthreads();
    const float* lg_b = logits + (size_t)b * TT * KK;
    const int* tg_b = targets + (size_t)b * TT;
    float ub = 0.f;
    for (int t = lane; t < TT; t += 64) {
        if (t < L) {
            int tg = tg_b[t];
            ub += lg_b[t * KK + tg];
            if (t >= 1) { int tp = tg_b[t - 1]; ub += s_trans[tp * KK + tg]; }
        }
    }
    #pragma unroll
    for (int d = 32; d >= 1; d >>= 1) ub += __shfl_xor(ub, d, 64);
    float a0 = lg_b[jj];
    float M = rlf(a0, 0);
    float s = (lane < KK) ? __expf(a0 - M) : 0.f;
    float sC = s, MC = M;
    const int Lm1 = L - 1;
    float pf[8];
    #pragma unroll
    for (int u = 0; u < 8; ++u) pf[u] = lg_b[(1 + u) * KK + jj];
    #pragma unroll 1
    for (int cc = 0; cc < 256; ++cc) {
        #pragma unroll
        for (int u = 0; u < 8; ++u) {
            const int t = 1 + cc * 8 + u;
            float lg = pf[u];
            int nrow = t + 8; if (nrow > TT - 1) nrow = TT - 1;
            pf[u] = lg_b[nrow * KK + jj];
            float eL = __expf(lg);
            float ac0 = 0.f, ac1 = 0.f, ac2 = 0.f, ac3 = 0.f;
            #pragma unroll
            for (int i = 0; i < KK; i += 4) {
                float s0 = rlf(s, i), s1 = rlf(s, i+1), s2 = rlf(s, i+2), s3 = rlf(s, i+3);
                ac0 = fmaf(s0, et[i], ac0);   ac1 = fmaf(s1, et[i+1], ac1);
                ac2 = fmaf(s2, et[i+2], ac2); ac3 = fmaf(s3, et[i+3], ac3);
            }
            float e = ((ac0 + ac1) + (ac2 + ac3)) * eL;
            bool cap = (t == Lm1);
            sC = cap ? e : sC;  MC = cap ? M : MC;
            float r = rlf(e, 0);
            s = e * __builtin_amdgcn_rcpf(r);
            M += __logf(r);
        }
    }
    float ssum = (lane < KK) ? sC : 0.f;
    #pragma unroll
    for (int d = 32; d >= 1; d >>= 1) ssum += __shfl_xor(ssum, d, 64);
    float log_norm = MC + __logf(ssum);
    if (lane == 0) out[b] = (L <= 0) ? 0.f : (ub - log_norm);
}

extern "C" void kernel_launch(void* const* d_in, const int* in_sizes, int n_in,
                              void* d_out, int out_size, void* d_ws, size_t ws_size,
                              hipStream_t stream) {
    const float* logits  = (const float*)d_in[0];
    const float* trans   = (const float*)d_in[1];
    const int*   targets = (const int*)  d_in[2];
    const int*   lens    = (const int*)  d_in[3];
    float*       out     = (float*)d_out;
    const int B = in_sizes[3];

    const size_t q64  = (size_t)B * 32 * KK * KK * sizeof(ushort_t);
    const size_t n64  = q64 + (size_t)B * 32 * sizeof(float);
    const size_t q128 = (size_t)B * 16 * KK * KK * sizeof(ushort_t);
    const size_t n128 = q128 + (size_t)B * 16 * sizeof(float);

    if (ws_size >= n64) {
        ushort_t* Qout = (ushort_t*)d_ws;
        float*    sig  = (float*)((char*)d_ws + q64);
        crf_seg_kernel<64, 32><<<dim3(B, 32), 64, 0, stream>>>(logits, trans, lens, Qout, sig);
        crf_comb_kernel<64, 32><<<B, 64, 0, stream>>>(logits, trans, targets, lens, Qout, sig, out);
    } else if (ws_size >= n128) {
        ushort_t* Qout = (ushort_t*)d_ws;
        float*    sig  = (float*)((char*)d_ws + q128);
        crf_seg_kernel<128, 16><<<dim3(B, 16), 64, 0, stream>>>(logits, trans, lens, Qout, sig);
        crf_comb_kernel<128, 16><<<B, 64, 0, stream>>>(logits, trans, targets, lens, Qout, sig, out);
    } else {
        crf_fwd_fallback<<<B, 64, 0, stream>>>(logits, trans, targets, lens, out);
    }
}

// Round 17
// 163.024 us; speedup vs baseline: 1.0425x; 1.0425x over previous
//
#include <hip/hip_runtime.h>
#include <hip/hip_bf16.h>
#include <math.h>

#define TT   2048
#define KK   48
#define KP   68             // epilogue staging pitch in ushorts

typedef __attribute__((ext_vector_type(8))) short bf16x8;
typedef __attribute__((ext_vector_type(4))) short bf16x4;
typedef __attribute__((ext_vector_type(4))) float f32x4;
typedef __attribute__((ext_vector_type(4))) unsigned int u32x4;
typedef __attribute__((ext_vector_type(2))) unsigned int u32x2;
typedef unsigned short ushort_t;

union FragU  { u32x4 u; bf16x8 h; };
union Frag16 { u32x2 u; bf16x4 h; };

#if defined(__has_builtin)
#  if __has_builtin(__builtin_amdgcn_mfma_f32_16x16x16bf16_1k)
#    define HAVE_MFMA16 1
#  endif
#endif
#ifndef HAVE_MFMA16
#  define HAVE_MFMA16 0
#endif

__device__ __forceinline__ float rlf(float x, int l) {
    return __uint_as_float((unsigned)__builtin_amdgcn_readlane((int)__float_as_uint(x), l));
}
__device__ __forceinline__ unsigned pk2(float a, float b) {
    __hip_bfloat162 h = __float22bfloat162_rn(make_float2(a, b));
    return *(unsigned*)&h;
}
// HW pack: single v_cvt_pk_bf16_f32 (RNE; gfx950-verified R7: -45us)
__device__ __forceinline__ unsigned pk2a(float a, float b) {
    unsigned r;
    asm("v_cvt_pk_bf16_f32 %0, %1, %2" : "=v"(r) : "v"(a), "v"(b));
    return r;
}

// ---------------- Kernel 1: segment matrix products (R17: exact K=48) -------
// R13-16 PMC: wall/step = MFMA-pipe(349cyc) + VALU(335cyc) -> pipes serialize
// per SIMD; hints (setprio R15) and dep-breaking (ping-pong R16) both null.
// Lever: cut the MFMA term. We paid K=64 for a K=48 product (upper 16 rows
// of the 2nd mfma were zeros). Replace 2nd mfma_16x16x32 with
// mfma_f32_16x16x16bf16_1k (K=16, half cost): 349 -> ~262 cyc/step.
// Bijection-cancel guarantees exactness (same k16(g,e)=4g+e feed both sides);
// B16 operand = exactly the rows-32..47 u32 pair we already produce.
template <int SEGT, int NSEGT>
__global__ __launch_bounds__(64, 4) void crf_seg_kernel(
    const float* __restrict__ logits,   // [B, T, K]
    const float* __restrict__ trans,    // [K, K]
    const int*   __restrict__ lens,     // [B]
    ushort_t*    __restrict__ Qout,     // [B*NSEGT][48*48] bf16 row-major
    float*       __restrict__ sigout)   // [B*NSEGT]
{
    constexpr int NFULLT = NSEGT - 1;
    const int b    = blockIdx.x;
    const int seg  = blockIdx.y;        // 0..NSEGT-1
    const int job  = b * NSEGT + seg;
    const int lane = threadIdx.x;
    const int c = lane & 15, g = lane >> 4;

    int t0, t1;
    if (seg < NFULLT) { t0 = SEGT * seg + 1; t1 = SEGT * seg + SEGT; }
    else {
        int L  = lens[b];
        int nf = (L >= 2) ? (L - 1) / SEGT : 0;
        if (nf > NFULLT) nf = NFULLT;
        t0 = SEGT * nf + 1; t1 = L - 1;   // may be empty (t1 < t0) -> Q = I
    }

    __shared__ float    eLs[2][64];
    __shared__ ushort_t Qst[KK * KP];    // epilogue staging only

    // A0[mt]: K=0..31 fragment, row r = 16mt + c, k = 16*(e>>2)+4g+(e&3).
    FragU A0[3];
    #pragma unroll
    for (int mt = 0; mt < 3; ++mt) {
        const int r = 16 * mt + c;
        #pragma unroll
        for (int ep = 0; ep < 4; ++ep) {
            int e0 = 2 * ep, e1 = 2 * ep + 1;
            int k0 = 16 * (e0 >> 2) + 4 * g + (e0 & 3);
            int k1 = 16 * (e1 >> 2) + 4 * g + (e1 & 3);
            A0[mt].u[ep] = pk2(__expf(trans[k0 * KK + r]),
                               __expf(trans[k1 * KK + r]));
        }
    }

#if HAVE_MFMA16
    // A16[mt]: K=32..47 fragment for 16x16x16, k = 32 + 4g + e (e=0..3).
    Frag16 A16[3];
    #pragma unroll
    for (int mt = 0; mt < 3; ++mt) {
        const int r = 16 * mt + c;
        #pragma unroll
        for (int ep = 0; ep < 2; ++ep) {
            int k0 = 32 + 4 * g + 2 * ep;
            A16[mt].u[ep] = pk2(__expf(trans[k0 * KK + r]),
                                __expf(trans[(k0 + 1) * KK + r]));
        }
    }
#else
    // Fallback: K=32..63 fragment (zeros past 47), bijection as before.
    FragU A1[3];
    #pragma unroll
    for (int mt = 0; mt < 3; ++mt) {
        const int r = 16 * mt + c;
        #pragma unroll
        for (int ep = 0; ep < 4; ++ep) {
            int e0 = 2 * ep, e1 = 2 * ep + 1;
            int k0 = 32 + 16 * (e0 >> 2) + 4 * g + (e0 & 3);
            int k1 = 32 + 16 * (e1 >> 2) + 4 * g + (e1 & 3);
            float v0 = (k0 < KK) ? __expf(trans[k0 * KK + r]) : 0.f;
            float v1 = (k1 < KK) ? __expf(trans[k1 * KK + r]) : 0.f;
            A1[mt].u[ep] = pk2(v0, v1);
        }
    }
#endif

    // Bf0 (k=0..31) and Bf1 (k=32..47) identity-column init; n = 16nt + c.
    FragU  Bf0[3];
    Frag16 Bf1[3];
    #pragma unroll
    for (int nt = 0; nt < 3; ++nt) {
        const int n = 16 * nt + c;
        #pragma unroll
        for (int ep = 0; ep < 4; ++ep) {
            int e0 = 2 * ep, e1 = 2 * ep + 1;
            int k0 = 16 * (e0 >> 2) + 4 * g + (e0 & 3);
            int k1 = 16 * (e1 >> 2) + 4 * g + (e1 & 3);
            unsigned lo = (k0 == n) ? 0x3F80u : 0u;
            unsigned hi = (k1 == n) ? 0x3F80u : 0u;
            Bf0[nt].u[ep] = (hi << 16) | lo;
        }
        #pragma unroll
        for (int ep = 0; ep < 2; ++ep) {
            int k0 = 32 + 4 * g + 2 * ep;
            unsigned lo = (k0 == n)     ? 0x3F80u : 0u;
            unsigned hi = (k0 + 1 == n) ? 0x3F80u : 0u;
            Bf1[nt].u[ep] = (hi << 16) | lo;
        }
    }

    const float* lg_b = logits + (size_t)b * TT * KK;
    const int jj = (lane < KK) ? lane : 0;
    float sg = 0.f;
    const int nsteps = t1 - t0 + 1;

    f32x4 z4 = {0.f, 0.f, 0.f, 0.f};
    asm("" : "+v"(z4));

#if HAVE_MFMA16
#define MF16(mt_, nt_, Y_) \
    __builtin_amdgcn_mfma_f32_16x16x16bf16_1k(A16[mt_].h, Bf1[nt_].h, Y_, 0, 0, 0)
#else
#define MF16(mt_, nt_, Y_) ({                                                 \
    FragU tb_; tb_.u[0] = Bf1[nt_].u[0]; tb_.u[1] = Bf1[nt_].u[1];            \
    tb_.u[2] = 0u; tb_.u[3] = 0u;                                             \
    __builtin_amdgcn_mfma_f32_16x16x32_bf16(A1[mt_].h, tb_.h, Y_, 0, 0, 0); })
#endif

#define COL_MFMA(nt_, Y0_, Y1_, Y2_)                                          \
        Y0_ = __builtin_amdgcn_mfma_f32_16x16x32_bf16(A0[0].h, Bf0[nt_].h, z4, 0, 0, 0); \
        Y1_ = __builtin_amdgcn_mfma_f32_16x16x32_bf16(A0[1].h, Bf0[nt_].h, z4, 0, 0, 0); \
        Y2_ = __builtin_amdgcn_mfma_f32_16x16x32_bf16(A0[2].h, Bf0[nt_].h, z4, 0, 0, 0); \
        Y0_ = MF16(0, nt_, Y0_);                                              \
        Y1_ = MF16(1, nt_, Y1_);                                              \
        Y2_ = MF16(2, nt_, Y2_);

// Scale col nt_'s Y regs by es, cvt to bf16, store into Bf0/Bf1 (guarded).
#define SCALE_STORE(nt_, Y0_, Y1_, Y2_)                                       \
    {                                                                         \
        f32x4 w0 = Y0_ * es0, w1 = Y1_ * es1, w2 = Y2_ * es2;                 \
        unsigned n0 = pk2a(w0[0], w0[1]);                                     \
        unsigned n1 = pk2a(w0[2], w0[3]);                                     \
        unsigned n2 = pk2a(w1[0], w1[1]);                                     \
        unsigned n3 = pk2a(w1[2], w1[3]);                                     \
        unsigned n4 = pk2a(w2[0], w2[1]);                                     \
        unsigned n5 = pk2a(w2[2], w2[3]);                                     \
        if (G_) {                                                             \
            Bf0[nt_].u[0] = jk ? Bf0[nt_].u[0] : n0;                          \
            Bf0[nt_].u[1] = jk ? Bf0[nt_].u[1] : n1;                          \
            Bf0[nt_].u[2] = jk ? Bf0[nt_].u[2] : n2;                          \
            Bf0[nt_].u[3] = jk ? Bf0[nt_].u[3] : n3;                          \
            Bf1[nt_].u[0] = jk ? Bf1[nt_].u[0] : n4;                          \
            Bf1[nt_].u[1] = jk ? Bf1[nt_].u[1] : n5;                          \
        } else {                                                              \
            Bf0[nt_].u[0] = n0; Bf0[nt_].u[1] = n1;                           \
            Bf0[nt_].u[2] = n2; Bf0[nt_].u[3] = n3;                           \
            Bf1[nt_].u[0] = n4; Bf1[nt_].u[1] = n5;                           \
        }                                                                     \
    }

// RN_: renormalize this step (every 4th: u_ = 3, 7).
#define STEP(u_, GG_, RN_)                                                    \
    {                                                                         \
        constexpr bool G_ = (GG_);                                            \
        const int i = 8 * cs + (u_);                                          \
        f32x4 eL0 = *(const f32x4*)&eLs[par][4 * g];                          \
        f32x4 eL1 = *(const f32x4*)&eLs[par][16 + 4 * g];                     \
        f32x4 eL2 = *(const f32x4*)&eLs[par][32 + 4 * g];                     \
        float lgn = pf[((u_) + 1) & 7];                                       \
        int nr = t0 + i + 9; if (nr > TT - 1) nr = TT - 1;                    \
        pf[((u_) + 1) & 7] = lg_b[nr * KK + jj];                              \
        if (lane < KK) eLs[par ^ 1][lane] = __expf(lgn);                      \
        const bool jk = G_ ? (i >= nsteps) : false;                           \
        f32x4 yA0, yA1, yA2, yB0, yB1, yB2;                                   \
        COL_MFMA(0, yA0, yA1, yA2)                                            \
        COL_MFMA(1, yB0, yB1, yB2)                                            \
        f32x4 es0, es1, es2;                                                  \
        if (RN_) {                                                            \
            float r = __uint_as_float((unsigned)                              \
                __builtin_amdgcn_readfirstlane((int)__float_as_uint(yA0[0])));\
            float rr = __builtin_amdgcn_rcpf(r);                              \
            sg += jk ? 0.f : __logf(r);                                       \
            es0 = eL0 * rr; es1 = eL1 * rr; es2 = eL2 * rr;                   \
        } else {                                                              \
            es0 = eL0; es1 = eL1; es2 = eL2;                                  \
        }                                                                     \
        SCALE_STORE(0, yA0, yA1, yA2)                                         \
        COL_MFMA(2, yA0, yA1, yA2)                                            \
        SCALE_STORE(1, yB0, yB1, yB2)                                         \
        SCALE_STORE(2, yA0, yA1, yA2)                                         \
        par ^= 1;                                                             \
    }

    int par = 0;
    if (nsteps > 0) {
        if (lane < KK) eLs[0][lane] = __expf(lg_b[t0 * KK + jj]);
        float pf[8];
        #pragma unroll
        for (int j = 1; j < 8; ++j) {
            int rj = t0 + j; if (rj > TT - 1) rj = TT - 1;
            pf[j] = lg_b[rj * KK + jj];
        }
        { int rj = t0 + 8; if (rj > TT - 1) rj = TT - 1; pf[0] = lg_b[rj * KK + jj]; }

        const int nchunks = (nsteps + 7) / 8;
        #pragma unroll 1
        for (int cs = 0; cs < nchunks - 1; ++cs) {
            STEP(0, false, false) STEP(1, false, false)
            STEP(2, false, false) STEP(3, false, true)
            STEP(4, false, false) STEP(5, false, false)
            STEP(6, false, false) STEP(7, false, true)
        }
        {   // last chunk: junk-guarded (freezes Bf/sg for i >= nsteps)
            const int cs = nchunks - 1;
            STEP(0, true, false) STEP(1, true, false)
            STEP(2, true, false) STEP(3, true, true)
            STEP(4, true, false) STEP(5, true, false)
            STEP(6, true, false) STEP(7, true, true)
        }
    }
#undef STEP
#undef COL_MFMA
#undef SCALE_STORE
#undef MF16

    // ---- epilogue: stage Bf (= final Q, bf16, maybe unnormalized) to LDS ----
    #pragma unroll
    for (int nt = 0; nt < 3; ++nt) {
        ushort_t* basep = &Qst[(16 * nt + c) * KP];
        *(unsigned*)&basep[4 * g]          = Bf0[nt].u[0];
        *(unsigned*)&basep[4 * g + 2]      = Bf0[nt].u[1];
        *(unsigned*)&basep[16 + 4 * g]     = Bf0[nt].u[2];
        *(unsigned*)&basep[16 + 4 * g + 2] = Bf0[nt].u[3];
        *(unsigned*)&basep[32 + 4 * g]     = Bf1[nt].u[0];
        *(unsigned*)&basep[32 + 4 * g + 2] = Bf1[nt].u[1];
    }
    __syncthreads();

    if (lane < KK) {
        const int m = lane;
        unsigned w[24];
        #pragma unroll
        for (int np = 0; np < 24; ++np) {
            unsigned lo = Qst[(2 * np)     * KP + m];
            unsigned hi = Qst[(2 * np + 1) * KP + m];
            w[np] = (hi << 16) | lo;
        }
        ushort_t* dst = Qout + (size_t)job * (KK * KK) + m * KK;
        #pragma unroll
        for (int i4 = 0; i4 < 6; ++i4) {
            uint4 o; o.x = w[4*i4]; o.y = w[4*i4+1]; o.z = w[4*i4+2]; o.w = w[4*i4+3];
            *(uint4*)&dst[8 * i4] = o;
        }
    }
    if (lane == 0) sigout[job] = sg;
}

// ---------------- Kernel 2: per-batch combine + scores (proven R5-R16) ----
template <int SEGT, int NSEGT>
__global__ __launch_bounds__(64) void crf_comb_kernel(
    const float* __restrict__ logits, const float* __restrict__ trans,
    const int* __restrict__ targets, const int* __restrict__ lens,
    const ushort_t* __restrict__ Qall, const float* __restrict__ sig,
    float* __restrict__ out)
{
    constexpr int NFULLT = NSEGT - 1;
    const int b = blockIdx.x, lane = threadIdx.x;
    const int jj = (lane < KK) ? lane : 0;
    const int L = lens[b];

    __shared__ float s_trans[KK * KK];
    for (int k = lane; k < KK * KK; k += 64) s_trans[k] = trans[k];
    __syncthreads();

    const float* lg_b = logits  + (size_t)b * TT * KK;
    const int*   tg_b = targets + (size_t)b * TT;

    float ub = 0.f;
    #pragma unroll 4
    for (int t = lane; t < TT; t += 64) {
        if (t < L) {
            int tg = tg_b[t];
            ub += lg_b[t * KK + tg];
            if (t >= 1) { int tp = tg_b[t - 1]; ub += s_trans[tp * KK + tg]; }
        }
    }
    #pragma unroll
    for (int d = 32; d >= 1; d >>= 1) ub += __shfl_xor(ub, d, 64);

    float log_norm = 0.f;
    if (L > 0) {
        float a0 = lg_b[jj];
        float M  = rlf(a0, 0);
        float s  = (lane < KK) ? __expf(a0 - M) : 0.f;
        int nf = (L >= 2) ? (L - 1) / SEGT : 0;
        if (nf > NFULLT) nf = NFULLT;

        for (int ci = 0; ci <= nf; ++ci) {           // full segments, then tail
            const int job = b * NSEGT + ((ci < nf) ? ci : NFULLT);
            const ushort_t* Qr = Qall + (size_t)job * (KK * KK) + jj * KK;
            unsigned rw[24];
            #pragma unroll
            for (int i4 = 0; i4 < 6; ++i4) {
                uint4 v = *(const uint4*)&Qr[8 * i4];
                rw[4*i4] = v.x; rw[4*i4+1] = v.y; rw[4*i4+2] = v.z; rw[4*i4+3] = v.w;
            }
            float acc = 0.f;
            #pragma unroll
            for (int ip = 0; ip < 24; ++ip) {
                unsigned u = rw[ip];
                float q0 = __uint_as_float(u << 16);
                float q1 = __uint_as_float(u & 0xFFFF0000u);
                acc = fmaf(rlf(s, 2 * ip),     q0, acc);
                acc = fmaf(rlf(s, 2 * ip + 1), q1, acc);
            }
            float r  = rlf(acc, 0);
            float rr = __builtin_amdgcn_rcpf(r);
            s = (lane < KK) ? acc * rr : 0.f;
            M += __logf(r) + sig[job];
        }

        float ssum = (lane < KK) ? s : 0.f;
        #pragma unroll
        for (int d = 32; d >= 1; d >>= 1) ssum += __shfl_xor(ssum, d, 64);
        log_norm = M + __logf(ssum);
    }

    if (lane == 0) out[b] = (L <= 0) ? 0.f : (ub - log_norm);
}

// ---------------- Round-3 fallback (ws too small) ----------------
__global__ __launch_bounds__(64) void crf_fwd_fallback(
    const float* __restrict__ logits, const float* __restrict__ trans,
    const int* __restrict__ targets, const int* __restrict__ lens,
    float* __restrict__ out)
{
    const int b = blockIdx.x, lane = threadIdx.x;
    const int jj = (lane < KK) ? lane : 0;
    const int L = lens[b];
    __shared__ float s_trans[KK * KK];
    for (int k = lane; k < KK * KK; k += 64) s_trans[k] = trans[k];
    float et[KK];
    #pragma unroll
    for (int i = 0; i < KK; ++i) et[i] = __expf(trans[i * KK + jj]);
    __syncthreads();
    const float* lg_b = logits + (size_t)b * TT * KK;
    const int* tg_b = targets + (size_t)b * TT;
    float ub = 0.f;
    for (int t = lane; t < TT; t += 64) {
        if (t < L) {
            int tg = tg_b[t];
            ub += lg_b[t * KK + tg];
            if (t >= 1) { int tp = tg_b[t - 1]; ub += s_trans[tp * KK + tg]; }
        }
    }
    #pragma unroll
    for (int d = 32; d >= 1; d >>= 1) ub += __shfl_xor(ub, d, 64);
    float a0 = lg_b[jj];
    float M = rlf(a0, 0);
    float s = (lane < KK) ? __expf(a0 - M) : 0.f;
    float sC = s, MC = M;
    const int Lm1 = L - 1;
    float pf[8];
    #pragma unroll
    for (int u = 0; u < 8; ++u) pf[u] = lg_b[(1 + u) * KK + jj];
    #pragma unroll 1
    for (int cc = 0; cc < 256; ++cc) {
        #pragma unroll
        for (int u = 0; u < 8; ++u) {
            const int t = 1 + cc * 8 + u;
            float lg = pf[u];
            int nrow = t + 8; if (nrow > TT - 1) nrow = TT - 1;
            pf[u] = lg_b[nrow * KK + jj];
            float eL = __expf(lg);
            float ac0 = 0.f, ac1 = 0.f, ac2 = 0.f, ac3 = 0.f;
            #pragma unroll
            for (int i = 0; i < KK; i += 4) {
                float s0 = rlf(s, i), s1 = rlf(s, i+1), s2 = rlf(s, i+2), s3 = rlf(s, i+3);
                ac0 = fmaf(s0, et[i], ac0);   ac1 = fmaf(s1, et[i+1], ac1);
                ac2 = fmaf(s2, et[i+2], ac2); ac3 = fmaf(s3, et[i+3], ac3);
            }
            float e = ((ac0 + ac1) + (ac2 + ac3)) * eL;
            bool cap = (t == Lm1);
            sC = cap ? e : sC;  MC = cap ? M : MC;
            float r = rlf(e, 0);
            s = e * __builtin_amdgcn_rcpf(r);
            M += __logf(r);
        }
    }
    float ssum = (lane < KK) ? sC : 0.f;
    #pragma unroll
    for (int d = 32; d >= 1; d >>= 1) ssum += __shfl_xor(ssum, d, 64);
    float log_norm = MC + __logf(ssum);
    if (lane == 0) out[b] = (L <= 0) ? 0.f : (ub - log_norm);
}

extern "C" void kernel_launch(void* const* d_in, const int* in_sizes, int n_in,
                              void* d_out, int out_size, void* d_ws, size_t ws_size,
                              hipStream_t stream) {
    const float* logits  = (const float*)d_in[0];
    const float* trans   = (const float*)d_in[1];
    const int*   targets = (const int*)  d_in[2];
    const int*   lens    = (const int*)  d_in[3];
    float*       out     = (float*)d_out;
    const int B = in_sizes[3];

    const size_t q64  = (size_t)B * 32 * KK * KK * sizeof(ushort_t);
    const size_t n64  = q64 + (size_t)B * 32 * sizeof(float);
    const size_t q128 = (size_t)B * 16 * KK * KK * sizeof(ushort_t);
    const size_t n128 = q128 + (size_t)B * 16 * sizeof(float);

    if (ws_size >= n64) {
        ushort_t* Qout = (ushort_t*)d_ws;
        float*    sig  = (float*)((char*)d_ws + q64);
        crf_seg_kernel<64, 32><<<dim3(B, 32), 64, 0, stream>>>(logits, trans, lens, Qout, sig);
        crf_comb_kernel<64, 32><<<B, 64, 0, stream>>>(logits, trans, targets, lens, Qout, sig, out);
    } else if (ws_size >= n128) {
        ushort_t* Qout = (ushort_t*)d_ws;
        float*    sig  = (float*)((char*)d_ws + q128);
        crf_seg_kernel<128, 16><<<dim3(B, 16), 64, 0, stream>>>(logits, trans, lens, Qout, sig);
        crf_comb_kernel<128, 16><<<B, 64, 0, stream>>>(logits, trans, targets, lens, Qout, sig, out);
    } else {
        crf_fwd_fallback<<<B, 64, 0, stream>>>(logits, trans, targets, lens, out);
    }
}

// Round 18
// 162.366 us; speedup vs baseline: 1.0467x; 1.0041x over previous
//
#include <hip/hip_runtime.h>
#include <hip/hip_bf16.h>
#include <math.h>

#define TT   2048
#define KK   48
#define KP   68             // epilogue staging pitch in ushorts

typedef __attribute__((ext_vector_type(8))) short bf16x8;
typedef __attribute__((ext_vector_type(4))) short bf16x4;
typedef __attribute__((ext_vector_type(4))) float f32x4;
typedef __attribute__((ext_vector_type(4))) unsigned int u32x4;
typedef __attribute__((ext_vector_type(2))) unsigned int u32x2;
typedef unsigned short ushort_t;

union FragU  { u32x4 u; bf16x8 h; };
union Frag16 { u32x2 u; bf16x4 h; };

#if defined(__has_builtin)
#  if __has_builtin(__builtin_amdgcn_mfma_f32_16x16x16bf16_1k)
#    define HAVE_MFMA16 1
#  endif
#endif
#ifndef HAVE_MFMA16
#  define HAVE_MFMA16 0
#endif

__device__ __forceinline__ float rlf(float x, int l) {
    return __uint_as_float((unsigned)__builtin_amdgcn_readlane((int)__float_as_uint(x), l));
}
__device__ __forceinline__ unsigned pk2(float a, float b) {
    __hip_bfloat162 h = __float22bfloat162_rn(make_float2(a, b));
    return *(unsigned*)&h;
}
// HW pack: single v_cvt_pk_bf16_f32 (RNE; gfx950-verified R7: -45us)
__device__ __forceinline__ unsigned pk2a(float a, float b) {
    unsigned r;
    asm("v_cvt_pk_bf16_f32 %0, %1, %2" : "=v"(r) : "v"(a), "v"(b));
    return r;
}

// ---------------- Kernel 1: segment matrix products (R18) -------------------
// R17 ledger (642 cyc/step): MFMA 262 (optimal for 48^3) + VALU 353 (vs ~110
// minimal useful). Suspect: (64,4)'s 128-reg unified cap forces y accumulators
// into AGPRs (arch VGPR_Count=56 << ~110 live) -> v_accvgpr_read per
// SCALE_STORE read (~36+/step). Resident waves measured ~3/SIMD anyway, so
// relax to (64,3) ~170 regs: allocator can keep y in arch VGPRs; occupancy
// unchanged, accvgpr traffic gone. Single-variable change vs R17.
template <int SEGT, int NSEGT>
__global__ __launch_bounds__(64, 3) void crf_seg_kernel(
    const float* __restrict__ logits,   // [B, T, K]
    const float* __restrict__ trans,    // [K, K]
    const int*   __restrict__ lens,     // [B]
    ushort_t*    __restrict__ Qout,     // [B*NSEGT][48*48] bf16 row-major
    float*       __restrict__ sigout)   // [B*NSEGT]
{
    constexpr int NFULLT = NSEGT - 1;
    const int b    = blockIdx.x;
    const int seg  = blockIdx.y;        // 0..NSEGT-1
    const int job  = b * NSEGT + seg;
    const int lane = threadIdx.x;
    const int c = lane & 15, g = lane >> 4;

    int t0, t1;
    if (seg < NFULLT) { t0 = SEGT * seg + 1; t1 = SEGT * seg + SEGT; }
    else {
        int L  = lens[b];
        int nf = (L >= 2) ? (L - 1) / SEGT : 0;
        if (nf > NFULLT) nf = NFULLT;
        t0 = SEGT * nf + 1; t1 = L - 1;   // may be empty (t1 < t0) -> Q = I
    }

    __shared__ float    eLs[2][64];
    __shared__ ushort_t Qst[KK * KP];    // epilogue staging only

    // A0[mt]: K=0..31 fragment, row r = 16mt + c, k = 16*(e>>2)+4g+(e&3).
    FragU A0[3];
    #pragma unroll
    for (int mt = 0; mt < 3; ++mt) {
        const int r = 16 * mt + c;
        #pragma unroll
        for (int ep = 0; ep < 4; ++ep) {
            int e0 = 2 * ep, e1 = 2 * ep + 1;
            int k0 = 16 * (e0 >> 2) + 4 * g + (e0 & 3);
            int k1 = 16 * (e1 >> 2) + 4 * g + (e1 & 3);
            A0[mt].u[ep] = pk2(__expf(trans[k0 * KK + r]),
                               __expf(trans[k1 * KK + r]));
        }
    }

#if HAVE_MFMA16
    // A16[mt]: K=32..47 fragment for 16x16x16, k = 32 + 4g + e (e=0..3).
    Frag16 A16[3];
    #pragma unroll
    for (int mt = 0; mt < 3; ++mt) {
        const int r = 16 * mt + c;
        #pragma unroll
        for (int ep = 0; ep < 2; ++ep) {
            int k0 = 32 + 4 * g + 2 * ep;
            A16[mt].u[ep] = pk2(__expf(trans[k0 * KK + r]),
                                __expf(trans[(k0 + 1) * KK + r]));
        }
    }
#else
    // Fallback: K=32..63 fragment (zeros past 47), bijection as before.
    FragU A1[3];
    #pragma unroll
    for (int mt = 0; mt < 3; ++mt) {
        const int r = 16 * mt + c;
        #pragma unroll
        for (int ep = 0; ep < 4; ++ep) {
            int e0 = 2 * ep, e1 = 2 * ep + 1;
            int k0 = 32 + 16 * (e0 >> 2) + 4 * g + (e0 & 3);
            int k1 = 32 + 16 * (e1 >> 2) + 4 * g + (e1 & 3);
            float v0 = (k0 < KK) ? __expf(trans[k0 * KK + r]) : 0.f;
            float v1 = (k1 < KK) ? __expf(trans[k1 * KK + r]) : 0.f;
            A1[mt].u[ep] = pk2(v0, v1);
        }
    }
#endif

    // Bf0 (k=0..31) and Bf1 (k=32..47) identity-column init; n = 16nt + c.
    FragU  Bf0[3];
    Frag16 Bf1[3];
    #pragma unroll
    for (int nt = 0; nt < 3; ++nt) {
        const int n = 16 * nt + c;
        #pragma unroll
        for (int ep = 0; ep < 4; ++ep) {
            int e0 = 2 * ep, e1 = 2 * ep + 1;
            int k0 = 16 * (e0 >> 2) + 4 * g + (e0 & 3);
            int k1 = 16 * (e1 >> 2) + 4 * g + (e1 & 3);
            unsigned lo = (k0 == n) ? 0x3F80u : 0u;
            unsigned hi = (k1 == n) ? 0x3F80u : 0u;
            Bf0[nt].u[ep] = (hi << 16) | lo;
        }
        #pragma unroll
        for (int ep = 0; ep < 2; ++ep) {
            int k0 = 32 + 4 * g + 2 * ep;
            unsigned lo = (k0 == n)     ? 0x3F80u : 0u;
            unsigned hi = (k0 + 1 == n) ? 0x3F80u : 0u;
            Bf1[nt].u[ep] = (hi << 16) | lo;
        }
    }

    const float* lg_b = logits + (size_t)b * TT * KK;
    const int jj = (lane < KK) ? lane : 0;
    float sg = 0.f;
    const int nsteps = t1 - t0 + 1;

    f32x4 z4 = {0.f, 0.f, 0.f, 0.f};
    asm("" : "+v"(z4));

#if HAVE_MFMA16
#define MF16(mt_, nt_, Y_) \
    __builtin_amdgcn_mfma_f32_16x16x16bf16_1k(A16[mt_].h, Bf1[nt_].h, Y_, 0, 0, 0)
#else
#define MF16(mt_, nt_, Y_) ({                                                 \
    FragU tb_; tb_.u[0] = Bf1[nt_].u[0]; tb_.u[1] = Bf1[nt_].u[1];            \
    tb_.u[2] = 0u; tb_.u[3] = 0u;                                             \
    __builtin_amdgcn_mfma_f32_16x16x32_bf16(A1[mt_].h, tb_.h, Y_, 0, 0, 0); })
#endif

#define COL_MFMA(nt_, Y0_, Y1_, Y2_)                                          \
        Y0_ = __builtin_amdgcn_mfma_f32_16x16x32_bf16(A0[0].h, Bf0[nt_].h, z4, 0, 0, 0); \
        Y1_ = __builtin_amdgcn_mfma_f32_16x16x32_bf16(A0[1].h, Bf0[nt_].h, z4, 0, 0, 0); \
        Y2_ = __builtin_amdgcn_mfma_f32_16x16x32_bf16(A0[2].h, Bf0[nt_].h, z4, 0, 0, 0); \
        Y0_ = MF16(0, nt_, Y0_);                                              \
        Y1_ = MF16(1, nt_, Y1_);                                              \
        Y2_ = MF16(2, nt_, Y2_);

// Scale col nt_'s Y regs by es, cvt to bf16, store into Bf0/Bf1 (guarded).
#define SCALE_STORE(nt_, Y0_, Y1_, Y2_)                                       \
    {                                                                         \
        f32x4 w0 = Y0_ * es0, w1 = Y1_ * es1, w2 = Y2_ * es2;                 \
        unsigned n0 = pk2a(w0[0], w0[1]);                                     \
        unsigned n1 = pk2a(w0[2], w0[3]);                                     \
        unsigned n2 = pk2a(w1[0], w1[1]);                                     \
        unsigned n3 = pk2a(w1[2], w1[3]);                                     \
        unsigned n4 = pk2a(w2[0], w2[1]);                                     \
        unsigned n5 = pk2a(w2[2], w2[3]);                                     \
        if (G_) {                                                             \
            Bf0[nt_].u[0] = jk ? Bf0[nt_].u[0] : n0;                          \
            Bf0[nt_].u[1] = jk ? Bf0[nt_].u[1] : n1;                          \
            Bf0[nt_].u[2] = jk ? Bf0[nt_].u[2] : n2;                          \
            Bf0[nt_].u[3] = jk ? Bf0[nt_].u[3] : n3;                          \
            Bf1[nt_].u[0] = jk ? Bf1[nt_].u[0] : n4;                          \
            Bf1[nt_].u[1] = jk ? Bf1[nt_].u[1] : n5;                          \
        } else {                                                              \
            Bf0[nt_].u[0] = n0; Bf0[nt_].u[1] = n1;                           \
            Bf0[nt_].u[2] = n2; Bf0[nt_].u[3] = n3;                           \
            Bf1[nt_].u[0] = n4; Bf1[nt_].u[1] = n5;                           \
        }                                                                     \
    }

// RN_: renormalize this step (every 4th: u_ = 3, 7).
#define STEP(u_, GG_, RN_)                                                    \
    {                                                                         \
        constexpr bool G_ = (GG_);                                            \
        const int i = 8 * cs + (u_);                                          \
        f32x4 eL0 = *(const f32x4*)&eLs[par][4 * g];                          \
        f32x4 eL1 = *(const f32x4*)&eLs[par][16 + 4 * g];                     \
        f32x4 eL2 = *(const f32x4*)&eLs[par][32 + 4 * g];                     \
        float lgn = pf[((u_) + 1) & 7];                                       \
        int nr = t0 + i + 9; if (nr > TT - 1) nr = TT - 1;                    \
        pf[((u_) + 1) & 7] = lg_b[nr * KK + jj];                              \
        if (lane < KK) eLs[par ^ 1][lane] = __expf(lgn);                      \
        const bool jk = G_ ? (i >= nsteps) : false;                           \
        f32x4 yA0, yA1, yA2, yB0, yB1, yB2;                                   \
        COL_MFMA(0, yA0, yA1, yA2)                                            \
        COL_MFMA(1, yB0, yB1, yB2)                                            \
        f32x4 es0, es1, es2;                                                  \
        if (RN_) {                                                            \
            float r = __uint_as_float((unsigned)                              \
                __builtin_amdgcn_readfirstlane((int)__float_as_uint(yA0[0])));\
            float rr = __builtin_amdgcn_rcpf(r);                              \
            sg += jk ? 0.f : __logf(r);                                       \
            es0 = eL0 * rr; es1 = eL1 * rr; es2 = eL2 * rr;                   \
        } else {                                                              \
            es0 = eL0; es1 = eL1; es2 = eL2;                                  \
        }                                                                     \
        SCALE_STORE(0, yA0, yA1, yA2)                                         \
        COL_MFMA(2, yA0, yA1, yA2)                                            \
        SCALE_STORE(1, yB0, yB1, yB2)                                         \
        SCALE_STORE(2, yA0, yA1, yA2)                                         \
        par ^= 1;                                                             \
    }

    int par = 0;
    if (nsteps > 0) {
        if (lane < KK) eLs[0][lane] = __expf(lg_b[t0 * KK + jj]);
        float pf[8];
        #pragma unroll
        for (int j = 1; j < 8; ++j) {
            int rj = t0 + j; if (rj > TT - 1) rj = TT - 1;
            pf[j] = lg_b[rj * KK + jj];
        }
        { int rj = t0 + 8; if (rj > TT - 1) rj = TT - 1; pf[0] = lg_b[rj * KK + jj]; }

        const int nchunks = (nsteps + 7) / 8;
        #pragma unroll 1
        for (int cs = 0; cs < nchunks - 1; ++cs) {
            STEP(0, false, false) STEP(1, false, false)
            STEP(2, false, false) STEP(3, false, true)
            STEP(4, false, false) STEP(5, false, false)
            STEP(6, false, false) STEP(7, false, true)
        }
        {   // last chunk: junk-guarded (freezes Bf/sg for i >= nsteps)
            const int cs = nchunks - 1;
            STEP(0, true, false) STEP(1, true, false)
            STEP(2, true, false) STEP(3, true, true)
            STEP(4, true, false) STEP(5, true, false)
            STEP(6, true, false) STEP(7, true, true)
        }
    }
#undef STEP
#undef COL_MFMA
#undef SCALE_STORE
#undef MF16

    // ---- epilogue: stage Bf (= final Q, bf16, maybe unnormalized) to LDS ----
    #pragma unroll
    for (int nt = 0; nt < 3; ++nt) {
        ushort_t* basep = &Qst[(16 * nt + c) * KP];
        *(unsigned*)&basep[4 * g]          = Bf0[nt].u[0];
        *(unsigned*)&basep[4 * g + 2]      = Bf0[nt].u[1];
        *(unsigned*)&basep[16 + 4 * g]     = Bf0[nt].u[2];
        *(unsigned*)&basep[16 + 4 * g + 2] = Bf0[nt].u[3];
        *(unsigned*)&basep[32 + 4 * g]     = Bf1[nt].u[0];
        *(unsigned*)&basep[32 + 4 * g + 2] = Bf1[nt].u[1];
    }
    __syncthreads();

    if (lane < KK) {
        const int m = lane;
        unsigned w[24];
        #pragma unroll
        for (int np = 0; np < 24; ++np) {
            unsigned lo = Qst[(2 * np)     * KP + m];
            unsigned hi = Qst[(2 * np + 1) * KP + m];
            w[np] = (hi << 16) | lo;
        }
        ushort_t* dst = Qout + (size_t)job * (KK * KK) + m * KK;
        #pragma unroll
        for (int i4 = 0; i4 < 6; ++i4) {
            uint4 o; o.x = w[4*i4]; o.y = w[4*i4+1]; o.z = w[4*i4+2]; o.w = w[4*i4+3];
            *(uint4*)&dst[8 * i4] = o;
        }
    }
    if (lane == 0) sigout[job] = sg;
}

// ---------------- Kernel 2: per-batch combine + scores (proven R5-R17) ----
template <int SEGT, int NSEGT>
__global__ __launch_bounds__(64) void crf_comb_kernel(
    const float* __restrict__ logits, const float* __restrict__ trans,
    const int* __restrict__ targets, const int* __restrict__ lens,
    const ushort_t* __restrict__ Qall, const float* __restrict__ sig,
    float* __restrict__ out)
{
    constexpr int NFULLT = NSEGT - 1;
    const int b = blockIdx.x, lane = threadIdx.x;
    const int jj = (lane < KK) ? lane : 0;
    const int L = lens[b];

    __shared__ float s_trans[KK * KK];
    for (int k = lane; k < KK * KK; k += 64) s_trans[k] = trans[k];
    __syncthreads();

    const float* lg_b = logits  + (size_t)b * TT * KK;
    const int*   tg_b = targets + (size_t)b * TT;

    float ub = 0.f;
    #pragma unroll 4
    for (int t = lane; t < TT; t += 64) {
        if (t < L) {
            int tg = tg_b[t];
            ub += lg_b[t * KK + tg];
            if (t >= 1) { int tp = tg_b[t - 1]; ub += s_trans[tp * KK + tg]; }
        }
    }
    #pragma unroll
    for (int d = 32; d >= 1; d >>= 1) ub += __shfl_xor(ub, d, 64);

    float log_norm = 0.f;
    if (L > 0) {
        float a0 = lg_b[jj];
        float M  = rlf(a0, 0);
        float s  = (lane < KK) ? __expf(a0 - M) : 0.f;
        int nf = (L >= 2) ? (L - 1) / SEGT : 0;
        if (nf > NFULLT) nf = NFULLT;

        for (int ci = 0; ci <= nf; ++ci) {           // full segments, then tail
            const int job = b * NSEGT + ((ci < nf) ? ci : NFULLT);
            const ushort_t* Qr = Qall + (size_t)job * (KK * KK) + jj * KK;
            unsigned rw[24];
            #pragma unroll
            for (int i4 = 0; i4 < 6; ++i4) {
                uint4 v = *(const uint4*)&Qr[8 * i4];
                rw[4*i4] = v.x; rw[4*i4+1] = v.y; rw[4*i4+2] = v.z; rw[4*i4+3] = v.w;
            }
            float acc = 0.f;
            #pragma unroll
            for (int ip = 0; ip < 24; ++ip) {
                unsigned u = rw[ip];
                float q0 = __uint_as_float(u << 16);
                float q1 = __uint_as_float(u & 0xFFFF0000u);
                acc = fmaf(rlf(s, 2 * ip),     q0, acc);
                acc = fmaf(rlf(s, 2 * ip + 1), q1, acc);
            }
            float r  = rlf(acc, 0);
            float rr = __builtin_amdgcn_rcpf(r);
            s = (lane < KK) ? acc * rr : 0.f;
            M += __logf(r) + sig[job];
        }

        float ssum = (lane < KK) ? s : 0.f;
        #pragma unroll
        for (int d = 32; d >= 1; d >>= 1) ssum += __shfl_xor(ssum, d, 64);
        log_norm = M + __logf(ssum);
    }

    if (lane == 0) out[b] = (L <= 0) ? 0.f : (ub - log_norm);
}

// ---------------- Round-3 fallback (ws too small) ----------------
__global__ __launch_bounds__(64) void crf_fwd_fallback(
    const float* __restrict__ logits, const float* __restrict__ trans,
    const int* __restrict__ targets, const int* __restrict__ lens,
    float* __restrict__ out)
{
    const int b = blockIdx.x, lane = threadIdx.x;
    const int jj = (lane < KK) ? lane : 0;
    const int L = lens[b];
    __shared__ float s_trans[KK * KK];
    for (int k = lane; k < KK * KK; k += 64) s_trans[k] = trans[k];
    float et[KK];
    #pragma unroll
    for (int i = 0; i < KK; ++i) et[i] = __expf(trans[i * KK + jj]);
    __syncthreads();
    const float* lg_b = logits + (size_t)b * TT * KK;
    const int* tg_b = targets + (size_t)b * TT;
    float ub = 0.f;
    for (int t = lane; t < TT; t += 64) {
        if (t < L) {
            int tg = tg_b[t];
            ub += lg_b[t * KK + tg];
            if (t >= 1) { int tp = tg_b[t - 1]; ub += s_trans[tp * KK + tg]; }
        }
    }
    #pragma unroll
    for (int d = 32; d >= 1; d >>= 1) ub += __shfl_xor(ub, d, 64);
    float a0 = lg_b[jj];
    float M = rlf(a0, 0);
    float s = (lane < KK) ? __expf(a0 - M) : 0.f;
    float sC = s, MC = M;
    const int Lm1 = L - 1;
    float pf[8];
    #pragma unroll
    for (int u = 0; u < 8; ++u) pf[u] = lg_b[(1 + u) * KK + jj];
    #pragma unroll 1
    for (int cc = 0; cc < 256; ++cc) {
        #pragma unroll
        for (int u = 0; u < 8; ++u) {
            const int t = 1 + cc * 8 + u;
            float lg = pf[u];
            int nrow = t + 8; if (nrow > TT - 1) nrow = TT - 1;
            pf[u] = lg_b[nrow * KK + jj];
            float eL = __expf(lg);
            float ac0 = 0.f, ac1 = 0.f, ac2 = 0.f, ac3 = 0.f;
            #pragma unroll
            for (int i = 0; i < KK; i += 4) {
                float s0 = rlf(s, i), s1 = rlf(s, i+1), s2 = rlf(s, i+2), s3 = rlf(s, i+3);
                ac0 = fmaf(s0, et[i], ac0);   ac1 = fmaf(s1, et[i+1], ac1);
                ac2 = fmaf(s2, et[i+2], ac2); ac3 = fmaf(s3, et[i+3], ac3);
            }
            float e = ((ac0 + ac1) + (ac2 + ac3)) * eL;
            bool cap = (t == Lm1);
            sC = cap ? e : sC;  MC = cap ? M : MC;
            float r = rlf(e, 0);
            s = e * __builtin_amdgcn_rcpf(r);
            M += __logf(r);
        }
    }
    float ssum = (lane < KK) ? sC : 0.f;
    #pragma unroll
    for (int d = 32; d >= 1; d >>= 1) ssum += __shfl_xor(ssum, d, 64);
    float log_norm = MC + __logf(ssum);
    if (lane == 0) out[b] = (L <= 0) ? 0.f : (ub - log_norm);
}

extern "C" void kernel_launch(void* const* d_in, const int* in_sizes, int n_in,
                              void* d_out, int out_size, void* d_ws, size_t ws_size,
                              hipStream_t stream) {
    const float* logits  = (const float*)d_in[0];
    const float* trans   = (const float*)d_in[1];
    const int*   targets = (const int*)  d_in[2];
    const int*   lens    = (const int*)  d_in[3];
    float*       out     = (float*)d_out;
    const int B = in_sizes[3];

    const size_t q64  = (size_t)B * 32 * KK * KK * sizeof(ushort_t);
    const size_t n64  = q64 + (size_t)B * 32 * sizeof(float);
    const size_t q128 = (size_t)B * 16 * KK * KK * sizeof(ushort_t);
    const size_t n128 = q128 + (size_t)B * 16 * sizeof(float);

    if (ws_size >= n64) {
        ushort_t* Qout = (ushort_t*)d_ws;
        float*    sig  = (float*)((char*)d_ws + q64);
        crf_seg_kernel<64, 32><<<dim3(B, 32), 64, 0, stream>>>(logits, trans, lens, Qout, sig);
        crf_comb_kernel<64, 32><<<B, 64, 0, stream>>>(logits, trans, targets, lens, Qout, sig, out);
    } else if (ws_size >= n128) {
        ushort_t* Qout = (ushort_t*)d_ws;
        float*    sig  = (float*)((char*)d_ws + q128);
        crf_seg_kernel<128, 16><<<dim3(B, 16), 64, 0, stream>>>(logits, trans, lens, Qout, sig);
        crf_comb_kernel<128, 16><<<B, 64, 0, stream>>>(logits, trans, targets, lens, Qout, sig, out);
    } else {
        crf_fwd_fallback<<<B, 64, 0, stream>>>(logits, trans, targets, lens, out);
    }
}